// Round 10
// baseline (96.009 us; speedup 1.0000x reference)
//
#include <hip/hip_runtime.h>
#include <math.h>

// 23-qubit statevector: 23 U3 gates (qubit q acts on global bit 22-q), then a
// CNOT cascade == Gray permutation out[y] = mid[y ^ (y>>1)].
// R10 gate partition:
//   pass_high: gates {0,1,2,3}u{14..22} (13 gates) — R9 structure + two new
//              DPP gates q20,q19 on its colf4 lane bits 0,1 (amp bits 2,3).
//              Chunk-level Gray-decode sigma=pxor9(row) folded into stores
//              (verified R4/R5/R8/R9).
//   pass_low : gates {4..13} = q18..q9 (10 gates) — LDS-FREE: one wave holds
//              a full gate orbit (64 amps/thread = 16 f4 re + 16 f4 im;
//              6 lane bits + 4 reg bits). In-chunk Gray gather
//              t_f4 = pxor12(x_f4) ^ 0xFFF*(c&1), comps reversed iff
//              parity(x_f4)^(c&1)  (verified R4/R5). In-place per chunk with
//              one vmcnt(0)+barrier between chunk reads and scattered writes.

#define NTOT (1u << 23)

typedef unsigned int u2 __attribute__((ext_vector_type(2)));

struct G8 { float r00,i00,r01,i01,r10,i10,r11,i11; };

__device__ __forceinline__ G8 u3_lane(const float* __restrict__ p, int q) {
    float a = p[3*q+0], b = p[3*q+1], c = p[3*q+2];
    float cb = cosf(b*0.5f), sb = sinf(b*0.5f);
    float ph = (a+c)*0.5f, m = (a-c)*0.5f;
    float cp = cosf(ph), sp = sinf(ph);
    float cm = cosf(m),  sm = sinf(m);
    G8 g;
    g.r00 =  cb*cp; g.i00 = -cb*sp;
    g.r01 = -sb*cm; g.i01 =  sb*sm;
    g.r10 =  sb*cm; g.i10 =  sb*sm;
    g.r11 =  cb*cp; g.i11 =  cb*sp;
    return g;
}

__device__ __forceinline__ float rdl(float v, int q) {
    return __uint_as_float(__builtin_amdgcn_readlane(__float_as_uint(v), q));
}
__device__ __forceinline__ G8 gread(const G8& m, int q) {
    G8 g;
    g.r00=rdl(m.r00,q); g.i00=rdl(m.i00,q);
    g.r01=rdl(m.r01,q); g.i01=rdl(m.i01,q);
    g.r10=rdl(m.r10,q); g.i10=rdl(m.i10,q);
    g.r11=rdl(m.r11,q); g.i11=rdl(m.i11,q);
    return g;
}

__device__ __forceinline__ void bfs(float& x0r, float& x0i, float& x1r, float& x1i, const G8& g) {
    float y0r = g.r00*x0r - g.i00*x0i + g.r01*x1r - g.i01*x1i;
    float y0i = g.r00*x0i + g.i00*x0r + g.r01*x1i + g.i01*x1r;
    float y1r = g.r10*x0r - g.i10*x0i + g.r11*x1r - g.i11*x1i;
    float y1i = g.r10*x0i + g.i10*x0r + g.r11*x1i + g.i11*x1r;
    x0r=y0r; x0i=y0i; x1r=y1r; x1i=y1i;
}
__device__ __forceinline__ void bf4v(float4& ar, float4& ai, float4& br, float4& bi, const G8& g) {
    bfs(ar.x, ai.x, br.x, bi.x, g);
    bfs(ar.y, ai.y, br.y, bi.y, g);
    bfs(ar.z, ai.z, br.z, bi.z, g);
    bfs(ar.w, ai.w, br.w, bi.w, g);
}
__device__ __forceinline__ void bfc0(float4& r, float4& i, const G8& g) {
    bfs(r.x, i.x, r.y, i.y, g); bfs(r.z, i.z, r.w, i.w, g);
}
__device__ __forceinline__ void bfc1(float4& r, float4& i, const G8& g) {
    bfs(r.x, i.x, r.z, i.z, g); bfs(r.y, i.y, r.w, i.w, g);
}
__device__ __forceinline__ void reg_gate0(float4 (&xr)[4], float4 (&xi)[4], const G8& g) {
    bf4v(xr[0],xi[0],xr[1],xi[1],g); bf4v(xr[2],xi[2],xr[3],xi[3],g);
}
__device__ __forceinline__ void reg_gate1(float4 (&xr)[4], float4 (&xi)[4], const G8& g) {
    bf4v(xr[0],xi[0],xr[2],xi[2],g); bf4v(xr[1],xi[1],xr[3],xi[3],g);
}
// generic register-bit gate for N-f4 arrays, bit K of the f4 index
template<int K, int N>
__device__ __forceinline__ void reg_gateK(float4 (&xr)[N], float4 (&xi)[N], const G8& g) {
#pragma unroll
    for (int j = 0; j < N; ++j)
        if (!(j & (1 << K)))
            bf4v(xr[j], xi[j], xr[j | (1 << K)], xi[j | (1 << K)], g);
}

// ---- lane-partner fetchers ----
__device__ __forceinline__ float p_dpp1(float x) {
    return __uint_as_float((unsigned)__builtin_amdgcn_update_dpp(
        0, (int)__float_as_uint(x), 0xB1, 0xF, 0xF, true));   // quad_perm [1,0,3,2]
}
__device__ __forceinline__ float p_dpp2(float x) {
    return __uint_as_float((unsigned)__builtin_amdgcn_update_dpp(
        0, (int)__float_as_uint(x), 0x4E, 0xF, 0xF, true));   // quad_perm [2,3,0,1]
}
__device__ __forceinline__ float p_swz4(float x) {   // xor lane^4 (BitMode)
    return __uint_as_float((unsigned)__builtin_amdgcn_ds_swizzle(
        (int)__float_as_uint(x), 0x101F));
}
__device__ __forceinline__ float p_swz8(float x) {   // xor lane^8 (BitMode)
    return __uint_as_float((unsigned)__builtin_amdgcn_ds_swizzle(
        (int)__float_as_uint(x), 0x201F));
}
__device__ __forceinline__ float p_x16(float x, int hi) {
#if __has_builtin(__builtin_amdgcn_permlane16_swap)
    u2 r = __builtin_amdgcn_permlane16_swap(__float_as_uint(x), __float_as_uint(x), false, false);
    return __uint_as_float(hi ? r[0] : r[1]);
#else
    (void)hi;
    return __uint_as_float((unsigned)__builtin_amdgcn_ds_swizzle(
        (int)__float_as_uint(x), 0x401F));                    // BitMode xor 16
#endif
}
__device__ __forceinline__ float p_x32(float x, int hi) {
#if __has_builtin(__builtin_amdgcn_permlane32_swap)
    u2 r = __builtin_amdgcn_permlane32_swap(__float_as_uint(x), __float_as_uint(x), false, false);
    return __uint_as_float(hi ? r[0] : r[1]);
#else
    (void)hi;
    return __shfl_xor(x, 32, 64);
#endif
}

// lane-bit gate, per-f4 fused fetch+combine (low register pressure), any N
#define MAKE_PGATE(NAME, FETCH)                                                     \
template<int N>                                                                     \
__device__ __forceinline__ void NAME(float4 (&xr)[N], float4 (&xi)[N],              \
                                     const G8& g, int bit, int hi) {                \
    float cor = bit ? g.r11 : g.r00, coi = bit ? g.i11 : g.i00;                     \
    float cpr = bit ? g.r10 : g.r01, cpi = bit ? g.i10 : g.i01;                     \
    (void)hi;                                                                       \
    _Pragma("unroll")                                                               \
    for (int i = 0; i < N; ++i) {                                                   \
        float4 pr, pi, nr, ni;                                                      \
        pr.x = FETCH(xr[i].x); pr.y = FETCH(xr[i].y);                               \
        pr.z = FETCH(xr[i].z); pr.w = FETCH(xr[i].w);                               \
        pi.x = FETCH(xi[i].x); pi.y = FETCH(xi[i].y);                               \
        pi.z = FETCH(xi[i].z); pi.w = FETCH(xi[i].w);                               \
        nr.x = cor*xr[i].x - coi*xi[i].x + cpr*pr.x - cpi*pi.x;                     \
        ni.x = cor*xi[i].x + coi*xr[i].x + cpr*pi.x + cpi*pr.x;                     \
        nr.y = cor*xr[i].y - coi*xi[i].y + cpr*pr.y - cpi*pi.y;                     \
        ni.y = cor*xi[i].y + coi*xr[i].y + cpr*pi.y + cpi*pr.y;                     \
        nr.z = cor*xr[i].z - coi*xi[i].z + cpr*pr.z - cpi*pi.z;                     \
        ni.z = cor*xi[i].z + coi*xr[i].z + cpr*pi.z + cpi*pr.z;                     \
        nr.w = cor*xr[i].w - coi*xi[i].w + cpr*pr.w - cpi*pi.w;                     \
        ni.w = cor*xi[i].w + coi*xr[i].w + cpr*pi.w + cpi*pr.w;                     \
        xr[i] = nr; xi[i] = ni;                                                     \
    }                                                                               \
}
#define F_DPP1(v) p_dpp1(v)
#define F_DPP2(v) p_dpp2(v)
#define F_SWZ4(v) p_swz4(v)
#define F_SWZ8(v) p_swz8(v)
#define F_X16(v)  p_x16(v, hi)
#define F_X32(v)  p_x32(v, hi)
MAKE_PGATE(gate_dpp1, F_DPP1)
MAKE_PGATE(gate_dpp2, F_DPP2)
MAKE_PGATE(gate_swz4, F_SWZ4)
MAKE_PGATE(gate_swz8, F_SWZ8)
MAKE_PGATE(gate_x16,  F_X16)
MAKE_PGATE(gate_x32,  F_X32)

__device__ __forceinline__ int pxor12(int x) { x^=x>>1; x^=x>>2; x^=x>>4; x^=x>>8; return x & 0xFFF; }
__device__ __forceinline__ int pxor9(int x)  { x^=x>>1; x^=x>>2; x^=x>>4; x^=x>>8; return x & 0x1FF; }

// ================= pass_high phases (R5/R9 mappings + q20,q19) =================
__device__ __forceinline__ void highA(float4 (&xr)[4], float4 (&xi)[4],
                                      const G8& my, int b1, int b2, int h16, int h32) {
    { G8 g = gread(my,22);
#pragma unroll
      for (int j = 0; j < 4; ++j) bfc0(xr[j], xi[j], g); }
    { G8 g = gread(my,21);
#pragma unroll
      for (int j = 0; j < 4; ++j) bfc1(xr[j], xi[j], g); }
    { G8 g = gread(my,20); gate_dpp1(xr, xi, g, b1, 0); }  // NEW: amp bit 2 = lane bit 0
    { G8 g = gread(my,19); gate_dpp2(xr, xi, g, b2, 0); }  // NEW: amp bit 3 = lane bit 1
    { G8 g = gread(my,5); reg_gate0(xr, xi, g); }
    { G8 g = gread(my,4); reg_gate1(xr, xi, g); }
    { G8 g = gread(my,7); gate_x16(xr, xi, g, h16, h16); }
    { G8 g = gread(my,6); gate_x32(xr, xi, g, h32, h32); }
}
__device__ __forceinline__ void wr_high(char* L, int l, int w,
                                        const float4 (&xr)[4], const float4 (&xi)[4]) {
    const int wslot = ((w << 8) | l) << 4;
#pragma unroll
    for (int j = 0; j < 4; ++j) {
        int a = wslot | (j << 10);
        *(float4*)(L + a) = xr[j];
        *(float4*)(L + a + 65536) = xi[j];
    }
}
__device__ __forceinline__ void rd_high(const char* L, int l, int w,
                                        float4 (&xr)[4], float4 (&xi)[4]) {
    const int sbase = (((l >> 1) & 7) | ((w & 3) << 4) | (((w >> 2) & 3) << 6)
                    | (((l >> 4) & 3) << 9) | ((l & 1) << 11)) << 4;
    constexpr int OFF[4] = {0, 8 << 4, 256 << 4, 264 << 4};
#pragma unroll
    for (int j = 0; j < 4; ++j) {
        int a = sbase | OFF[j];
        xr[j] = *(const float4*)(L + a);
        xi[j] = *(const float4*)(L + a + 65536);
    }
}
__device__ __forceinline__ void highB_store(float4 (&xr)[4], float4 (&xi)[4],
        const G8& my, int l, int w, int blk, int b1, int h16, int h32,
        float4* __restrict__ OR4, float4* __restrict__ OI4) {
    { G8 g = gread(my,8); reg_gate0(xr, xi, g); }
    { G8 g = gread(my,3); reg_gate1(xr, xi, g); }
    { G8 g = gread(my,0); gate_dpp1(xr, xi, g, b1, 0); }
    { G8 g = gread(my,2); gate_x16(xr, xi, g, h16, h16); }
    { G8 g = gread(my,1); gate_x32(xr, xi, g, h32, h32); }
    const int row_base = ((w & 15) << 1) | (((l >> 4) & 3) << 6) | ((l & 1) << 8);
    const int sg = pxor9(row_base);
    const size_t ob = ((size_t)blk << 3) | (size_t)((l >> 1) & 7);
    constexpr int SJ[4] = {0, 0x01, 0x3F, 0x3E};
#pragma unroll
    for (int j = 0; j < 4; ++j) {
        size_t F = (((size_t)(sg ^ SJ[j])) << 12) | ob;
        OR4[F] = xr[j]; OI4[F] = xi[j];
    }
}

__global__ __launch_bounds__(1024, 4)
void pass_high(const float* __restrict__ in_re, const float* __restrict__ in_im,
               const float* __restrict__ param,
               float* __restrict__ out_re, float* __restrict__ out_im) {
    __shared__ __align__(16) char L[131072];
    const int tid = threadIdx.x;
    const int l = tid & 63, w = tid >> 6;
    const int blkA = blockIdx.x, blkB = blockIdx.x + 256;

    const float4* R4p = (const float4*)in_re;
    const float4* I4p = (const float4*)in_im;
    float4 ar[4], ai[4], br_[4], bi_[4];
    const int rb = (l >> 3) | (w << 5);
    const size_t gA = ((size_t)blkA << 3) | (size_t)(l & 7);
    const size_t gB = ((size_t)blkB << 3) | (size_t)(l & 7);
#pragma unroll
    for (int j = 0; j < 4; ++j) {
        size_t gi = (((size_t)(rb | (j << 3))) << 12) | gA;
        ar[j] = R4p[gi]; ai[j] = I4p[gi];
    }
#pragma unroll
    for (int j = 0; j < 4; ++j) {
        size_t gi = (((size_t)(rb | (j << 3))) << 12) | gB;
        br_[j] = R4p[gi]; bi_[j] = I4p[gi];
    }
    G8 my = u3_lane(param, l < 23 ? l : 22);   // trig overlaps loads
    const int b1  = l & 1, b2 = (l >> 1) & 1;
    const int h16 = (l >> 4) & 1, h32 = (l >> 5) & 1;
    float4* OR4 = (float4*)out_re;
    float4* OI4 = (float4*)out_im;

    // Tile A
    highA(ar, ai, my, b1, b2, h16, h32);
    wr_high(L, l, w, ar, ai);                  // LDS virgin: no pre-sync
    __syncthreads();
    rd_high(L, l, w, ar, ai);
    highB_store(ar, ai, my, l, w, blkA, b1, h16, h32, OR4, OI4);  // stores async
    // Tile B epoch A overlaps tile A store drain
    highA(br_, bi_, my, b1, b2, h16, h32);
    __syncthreads();                           // all A RT-reads complete
    wr_high(L, l, w, br_, bi_);
    __syncthreads();
    rd_high(L, l, w, br_, bi_);
    highB_store(br_, bi_, my, l, w, blkB, b1, h16, h32, OR4, OI4);
}

// ================= pass_low: LDS-free, gates q18..q9 (amp bits 4..13) ========
// 512 blocks x 256 thr; block owns chunk c = blockIdx (amp bits 14..22).
// wave w (0..3) = amp bits 2,3 (ungated here). Thread: 16 f4 re + 16 f4 im.
// x_f4 = (j<<8) | (l<<2) | w : j (4 bits) -> amp 10..13 (q12..q9, reg gates);
// l (6 bits) -> amp 4..9 (q18..q13: dpp1,dpp2,swz4,swz8,x16,x32).
// Store: t_f4 = pxor12(x_f4) ^ 0xFFF*(c&1); comps (x,y,w,z) reversed iff
// parity(x_f4)^(c&1). In-place: vmcnt(0)+barrier between loads and stores.
__global__ __launch_bounds__(256, 2)
void pass_low(float* __restrict__ sre, float* __restrict__ sim,
              const float* __restrict__ param) {
    const int tid = threadIdx.x, c = blockIdx.x;
    const int l = tid & 63, w = tid >> 6;
    G8 my = u3_lane(param, l < 23 ? l : 22);
    float4 xr[16], xi[16];

    float4* R4p = (float4*)sre;
    float4* I4p = (float4*)sim;
    const size_t cb = ((size_t)c) << 12;
    const int base = (l << 2) | w;
#pragma unroll
    for (int j = 0; j < 16; ++j) {
        size_t fi = cb | (size_t)((j << 8) | base);
        xr[j] = R4p[fi]; xi[j] = I4p[fi];
    }
    // drain all chunk reads before any in-place scattered store (cross-wave)
    asm volatile("s_waitcnt vmcnt(0)" ::: "memory");
    __syncthreads();

    // 6 lane gates
    { G8 g = gread(my,18); gate_dpp1(xr, xi, g, l & 1, 0); }
    { G8 g = gread(my,17); gate_dpp2(xr, xi, g, (l >> 1) & 1, 0); }
    { G8 g = gread(my,16); gate_swz4(xr, xi, g, (l >> 2) & 1, 0); }
    { G8 g = gread(my,15); gate_swz8(xr, xi, g, (l >> 3) & 1, 0); }
    { G8 g = gread(my,14); gate_x16(xr, xi, g, (l >> 4) & 1, (l >> 4) & 1); }
    { G8 g = gread(my,13); gate_x32(xr, xi, g, (l >> 5) & 1, (l >> 5) & 1); }
    // 4 reg gates (j bits 0..3 = amp bits 10..13)
    { G8 g = gread(my,12); reg_gateK<0>(xr, xi, g); }
    { G8 g = gread(my,11); reg_gateK<1>(xr, xi, g); }
    { G8 g = gread(my,10); reg_gateK<2>(xr, xi, g); }
    { G8 g = gread(my, 9); reg_gateK<3>(xr, xi, g); }

    // Gray-gather store (verified R4/R5 formulas)
    const int pxb = pxor12(base);
    const int codd = c & 1;
    const int A12 = codd ? 0xFFF : 0;
    constexpr int PXJ[16] = {0x000,0x1FF,0x3FF,0x200,0x7FF,0x600,0x400,0x5FF,
                             0xFFF,0xE00,0xC00,0xDFF,0x800,0x9FF,0xBFF,0xA00};
#pragma unroll
    for (int j = 0; j < 16; ++j) {
        int pxj = pxb ^ PXJ[j];
        int of4 = pxj ^ A12;
        int b = (pxj ^ codd) & 1;
        float s0r = xr[j].x, s1r = xr[j].y, s2r = xr[j].w, s3r = xr[j].z;
        float s0i = xi[j].x, s1i = xi[j].y, s2i = xi[j].w, s3i = xi[j].z;
        float o0r = b ? s3r : s0r, o1r = b ? s2r : s1r, o2r = b ? s1r : s2r, o3r = b ? s0r : s3r;
        float o0i = b ? s3i : s0i, o1i = b ? s2i : s1i, o2i = b ? s1i : s2i, o3i = b ? s0i : s3i;
        size_t oo = cb | (size_t)of4;
        R4p[oo] = make_float4(o0r, o1r, o2r, o3r);
        I4p[oo] = make_float4(o0i, o1i, o2i, o3i);
    }
}

extern "C" void kernel_launch(void* const* d_in, const int* in_sizes, int n_in,
                              void* d_out, int out_size, void* d_ws, size_t ws_size,
                              hipStream_t stream) {
    (void)in_sizes; (void)n_in; (void)d_ws; (void)ws_size; (void)out_size;
    const float* in_re = (const float*)d_in[0];
    const float* in_im = (const float*)d_in[1];
    const float* param = (const float*)d_in[2];
    float* out_re = (float*)d_out;
    float* out_im = (float*)d_out + NTOT;

    pass_high<<<256, 1024, 0, stream>>>(in_re, in_im, param, out_re, out_im);
    pass_low <<<512, 256, 0, stream>>>(out_re, out_im, param);
}

// Round 11
// 77.670 us; speedup vs baseline: 1.2361x; 1.2361x over previous
//
#include <hip/hip_runtime.h>
#include <math.h>

// 23-qubit statevector: 23 U3 gates (qubit q acts on global bit 22-q), then a
// CNOT cascade == Gray permutation out[y] = mid[y ^ (y>>1)].
// Partition (R10-verified): pass_high gates {0,1,2,3}u{14..22} (13 gates) +
// chunk-level Gray-decode sigma=pxor9(row); pass_low gates {4..13} (10 gates)
// + in-chunk Gray gather t = pxor12(x) ^ 0xFFF*(c&1), comps reversed iff
// parity(x)^(c&1)  (verified R4/R5/R10).
// R11 pass_low: coalesced-store redesign. Post-RT ownership chosen as
//   x_post = g8((w<<4)|(l&15)) | l4<<8 | l5<<9 | j'<<10   (g8(v)=v^(v>>1))
// so the store address t = pxor12(x_post) telescopes to
//   t = ((l&15)|(w<<4)) ^ 0xFF*S | S<<8 | (l5^j0^j1)<<9 | (j0^j1)<<10 | j1<<11,
//   S = l4^l5^j0^j1
// -> per store instruction: four 16-lane x 16B = 256 B contiguous segments
// (vs 16B scatter before). Gates: pre-RT amp{4..7} lane (masks 4,8,16,32),
// amp{8,9} reg; post-RT amp{10,11} lane (masks 16,32), amp{12,13} reg.

#define NTOT (1u << 23)

typedef unsigned int u2 __attribute__((ext_vector_type(2)));

struct G8 { float r00,i00,r01,i01,r10,i10,r11,i11; };

__device__ __forceinline__ G8 u3_lane(const float* __restrict__ p, int q) {
    float a = p[3*q+0], b = p[3*q+1], c = p[3*q+2];
    float cb = cosf(b*0.5f), sb = sinf(b*0.5f);
    float ph = (a+c)*0.5f, m = (a-c)*0.5f;
    float cp = cosf(ph), sp = sinf(ph);
    float cm = cosf(m),  sm = sinf(m);
    G8 g;
    g.r00 =  cb*cp; g.i00 = -cb*sp;
    g.r01 = -sb*cm; g.i01 =  sb*sm;
    g.r10 =  sb*cm; g.i10 =  sb*sm;
    g.r11 =  cb*cp; g.i11 =  cb*sp;
    return g;
}

__device__ __forceinline__ float rdl(float v, int q) {
    return __uint_as_float(__builtin_amdgcn_readlane(__float_as_uint(v), q));
}
__device__ __forceinline__ G8 gread(const G8& m, int q) {
    G8 g;
    g.r00=rdl(m.r00,q); g.i00=rdl(m.i00,q);
    g.r01=rdl(m.r01,q); g.i01=rdl(m.i01,q);
    g.r10=rdl(m.r10,q); g.i10=rdl(m.i10,q);
    g.r11=rdl(m.r11,q); g.i11=rdl(m.i11,q);
    return g;
}

__device__ __forceinline__ void bfs(float& x0r, float& x0i, float& x1r, float& x1i, const G8& g) {
    float y0r = g.r00*x0r - g.i00*x0i + g.r01*x1r - g.i01*x1i;
    float y0i = g.r00*x0i + g.i00*x0r + g.r01*x1i + g.i01*x1r;
    float y1r = g.r10*x0r - g.i10*x0i + g.r11*x1r - g.i11*x1i;
    float y1i = g.r10*x0i + g.i10*x0r + g.r11*x1i + g.i11*x1r;
    x0r=y0r; x0i=y0i; x1r=y1r; x1i=y1i;
}
__device__ __forceinline__ void bf4v(float4& ar, float4& ai, float4& br, float4& bi, const G8& g) {
    bfs(ar.x, ai.x, br.x, bi.x, g);
    bfs(ar.y, ai.y, br.y, bi.y, g);
    bfs(ar.z, ai.z, br.z, bi.z, g);
    bfs(ar.w, ai.w, br.w, bi.w, g);
}
__device__ __forceinline__ void bfc0(float4& r, float4& i, const G8& g) {
    bfs(r.x, i.x, r.y, i.y, g); bfs(r.z, i.z, r.w, i.w, g);
}
__device__ __forceinline__ void bfc1(float4& r, float4& i, const G8& g) {
    bfs(r.x, i.x, r.z, i.z, g); bfs(r.y, i.y, r.w, i.w, g);
}
__device__ __forceinline__ void reg_gate0(float4 (&xr)[4], float4 (&xi)[4], const G8& g) {
    bf4v(xr[0],xi[0],xr[1],xi[1],g); bf4v(xr[2],xi[2],xr[3],xi[3],g);
}
__device__ __forceinline__ void reg_gate1(float4 (&xr)[4], float4 (&xi)[4], const G8& g) {
    bf4v(xr[0],xi[0],xr[2],xi[2],g); bf4v(xr[1],xi[1],xr[3],xi[3],g);
}

// ---- lane-partner fetchers ----
__device__ __forceinline__ float p_dpp1(float x) {
    return __uint_as_float((unsigned)__builtin_amdgcn_update_dpp(
        0, (int)__float_as_uint(x), 0xB1, 0xF, 0xF, true));   // quad_perm [1,0,3,2]
}
__device__ __forceinline__ float p_dpp2(float x) {
    return __uint_as_float((unsigned)__builtin_amdgcn_update_dpp(
        0, (int)__float_as_uint(x), 0x4E, 0xF, 0xF, true));   // quad_perm [2,3,0,1]
}
__device__ __forceinline__ float p_swz4(float x) {   // xor lane^4 (BitMode)
    return __uint_as_float((unsigned)__builtin_amdgcn_ds_swizzle(
        (int)__float_as_uint(x), 0x101F));
}
__device__ __forceinline__ float p_swz8(float x) {   // xor lane^8 (BitMode)
    return __uint_as_float((unsigned)__builtin_amdgcn_ds_swizzle(
        (int)__float_as_uint(x), 0x201F));
}
__device__ __forceinline__ float p_x16(float x, int hi) {
#if __has_builtin(__builtin_amdgcn_permlane16_swap)
    u2 r = __builtin_amdgcn_permlane16_swap(__float_as_uint(x), __float_as_uint(x), false, false);
    return __uint_as_float(hi ? r[0] : r[1]);
#else
    (void)hi;
    return __uint_as_float((unsigned)__builtin_amdgcn_ds_swizzle(
        (int)__float_as_uint(x), 0x401F));                    // BitMode xor 16
#endif
}
__device__ __forceinline__ float p_x32(float x, int hi) {
#if __has_builtin(__builtin_amdgcn_permlane32_swap)
    u2 r = __builtin_amdgcn_permlane32_swap(__float_as_uint(x), __float_as_uint(x), false, false);
    return __uint_as_float(hi ? r[0] : r[1]);
#else
    (void)hi;
    return __shfl_xor(x, 32, 64);
#endif
}

// lane-bit gate, per-f4 fused fetch+combine
#define MAKE_PGATE(NAME, FETCH)                                                     \
__device__ __forceinline__ void NAME(float4 (&xr)[4], float4 (&xi)[4],              \
                                     const G8& g, int bit, int hi) {                \
    float cor = bit ? g.r11 : g.r00, coi = bit ? g.i11 : g.i00;                     \
    float cpr = bit ? g.r10 : g.r01, cpi = bit ? g.i10 : g.i01;                     \
    (void)hi;                                                                       \
    _Pragma("unroll")                                                               \
    for (int i = 0; i < 4; ++i) {                                                   \
        float4 pr, pi, nr, ni;                                                      \
        pr.x = FETCH(xr[i].x); pr.y = FETCH(xr[i].y);                               \
        pr.z = FETCH(xr[i].z); pr.w = FETCH(xr[i].w);                               \
        pi.x = FETCH(xi[i].x); pi.y = FETCH(xi[i].y);                               \
        pi.z = FETCH(xi[i].z); pi.w = FETCH(xi[i].w);                               \
        nr.x = cor*xr[i].x - coi*xi[i].x + cpr*pr.x - cpi*pi.x;                     \
        ni.x = cor*xi[i].x + coi*xr[i].x + cpr*pi.x + cpi*pr.x;                     \
        nr.y = cor*xr[i].y - coi*xi[i].y + cpr*pr.y - cpi*pi.y;                     \
        ni.y = cor*xi[i].y + coi*xr[i].y + cpr*pi.y + cpi*pr.y;                     \
        nr.z = cor*xr[i].z - coi*xi[i].z + cpr*pr.z - cpi*pi.z;                     \
        ni.z = cor*xi[i].z + coi*xr[i].z + cpr*pi.z + cpi*pr.z;                     \
        nr.w = cor*xr[i].w - coi*xi[i].w + cpr*pr.w - cpi*pi.w;                     \
        ni.w = cor*xi[i].w + coi*xr[i].w + cpr*pi.w + cpi*pr.w;                     \
        xr[i] = nr; xi[i] = ni;                                                     \
    }                                                                               \
}
#define F_DPP1(v) p_dpp1(v)
#define F_DPP2(v) p_dpp2(v)
#define F_SWZ4(v) p_swz4(v)
#define F_SWZ8(v) p_swz8(v)
#define F_X16(v)  p_x16(v, hi)
#define F_X32(v)  p_x32(v, hi)
MAKE_PGATE(gate_dpp1, F_DPP1)
MAKE_PGATE(gate_dpp2, F_DPP2)
MAKE_PGATE(gate_swz4, F_SWZ4)
MAKE_PGATE(gate_swz8, F_SWZ8)
MAKE_PGATE(gate_x16,  F_X16)
MAKE_PGATE(gate_x32,  F_X32)

__device__ __forceinline__ int pxor9(int x)  { x^=x>>1; x^=x>>2; x^=x>>4; x^=x>>8; return x & 0x1FF; }

// ================= pass_high (R10 verbatim, verified passing) ================
__device__ __forceinline__ void highA(float4 (&xr)[4], float4 (&xi)[4],
                                      const G8& my, int b1, int b2, int h16, int h32) {
    { G8 g = gread(my,22);
#pragma unroll
      for (int j = 0; j < 4; ++j) bfc0(xr[j], xi[j], g); }
    { G8 g = gread(my,21);
#pragma unroll
      for (int j = 0; j < 4; ++j) bfc1(xr[j], xi[j], g); }
    { G8 g = gread(my,20); gate_dpp1(xr, xi, g, b1, 0); }  // amp bit 2 = lane bit 0
    { G8 g = gread(my,19); gate_dpp2(xr, xi, g, b2, 0); }  // amp bit 3 = lane bit 1
    { G8 g = gread(my,5); reg_gate0(xr, xi, g); }
    { G8 g = gread(my,4); reg_gate1(xr, xi, g); }
    { G8 g = gread(my,7); gate_x16(xr, xi, g, h16, h16); }
    { G8 g = gread(my,6); gate_x32(xr, xi, g, h32, h32); }
}
__device__ __forceinline__ void wr_high(char* L, int l, int w,
                                        const float4 (&xr)[4], const float4 (&xi)[4]) {
    const int wslot = ((w << 8) | l) << 4;
#pragma unroll
    for (int j = 0; j < 4; ++j) {
        int a = wslot | (j << 10);
        *(float4*)(L + a) = xr[j];
        *(float4*)(L + a + 65536) = xi[j];
    }
}
__device__ __forceinline__ void rd_high(const char* L, int l, int w,
                                        float4 (&xr)[4], float4 (&xi)[4]) {
    const int sbase = (((l >> 1) & 7) | ((w & 3) << 4) | (((w >> 2) & 3) << 6)
                    | (((l >> 4) & 3) << 9) | ((l & 1) << 11)) << 4;
    constexpr int OFF[4] = {0, 8 << 4, 256 << 4, 264 << 4};
#pragma unroll
    for (int j = 0; j < 4; ++j) {
        int a = sbase | OFF[j];
        xr[j] = *(const float4*)(L + a);
        xi[j] = *(const float4*)(L + a + 65536);
    }
}
__device__ __forceinline__ void highB_store(float4 (&xr)[4], float4 (&xi)[4],
        const G8& my, int l, int w, int blk, int b1, int h16, int h32,
        float4* __restrict__ OR4, float4* __restrict__ OI4) {
    { G8 g = gread(my,8); reg_gate0(xr, xi, g); }
    { G8 g = gread(my,3); reg_gate1(xr, xi, g); }
    { G8 g = gread(my,0); gate_dpp1(xr, xi, g, b1, 0); }
    { G8 g = gread(my,2); gate_x16(xr, xi, g, h16, h16); }
    { G8 g = gread(my,1); gate_x32(xr, xi, g, h32, h32); }
    const int row_base = ((w & 15) << 1) | (((l >> 4) & 3) << 6) | ((l & 1) << 8);
    const int sg = pxor9(row_base);
    const size_t ob = ((size_t)blk << 3) | (size_t)((l >> 1) & 7);
    constexpr int SJ[4] = {0, 0x01, 0x3F, 0x3E};
#pragma unroll
    for (int j = 0; j < 4; ++j) {
        size_t F = (((size_t)(sg ^ SJ[j])) << 12) | ob;
        OR4[F] = xr[j]; OI4[F] = xi[j];
    }
}

__global__ __launch_bounds__(1024, 4)
void pass_high(const float* __restrict__ in_re, const float* __restrict__ in_im,
               const float* __restrict__ param,
               float* __restrict__ out_re, float* __restrict__ out_im) {
    __shared__ __align__(16) char L[131072];
    const int tid = threadIdx.x;
    const int l = tid & 63, w = tid >> 6;
    const int blkA = blockIdx.x, blkB = blockIdx.x + 256;

    const float4* R4p = (const float4*)in_re;
    const float4* I4p = (const float4*)in_im;
    float4 ar[4], ai[4], br_[4], bi_[4];
    const int rb = (l >> 3) | (w << 5);
    const size_t gA = ((size_t)blkA << 3) | (size_t)(l & 7);
    const size_t gB = ((size_t)blkB << 3) | (size_t)(l & 7);
#pragma unroll
    for (int j = 0; j < 4; ++j) {
        size_t gi = (((size_t)(rb | (j << 3))) << 12) | gA;
        ar[j] = R4p[gi]; ai[j] = I4p[gi];
    }
#pragma unroll
    for (int j = 0; j < 4; ++j) {
        size_t gi = (((size_t)(rb | (j << 3))) << 12) | gB;
        br_[j] = R4p[gi]; bi_[j] = I4p[gi];
    }
    G8 my = u3_lane(param, l < 23 ? l : 22);   // trig overlaps loads
    const int b1  = l & 1, b2 = (l >> 1) & 1;
    const int h16 = (l >> 4) & 1, h32 = (l >> 5) & 1;
    float4* OR4 = (float4*)out_re;
    float4* OI4 = (float4*)out_im;

    // Tile A
    highA(ar, ai, my, b1, b2, h16, h32);
    wr_high(L, l, w, ar, ai);                  // LDS virgin: no pre-sync
    __syncthreads();
    rd_high(L, l, w, ar, ai);
    highB_store(ar, ai, my, l, w, blkA, b1, h16, h32, OR4, OI4);  // stores async
    // Tile B epoch A overlaps tile A store drain
    highA(br_, bi_, my, b1, b2, h16, h32);
    __syncthreads();                           // all A RT-reads complete
    wr_high(L, l, w, br_, bi_);
    __syncthreads();
    rd_high(L, l, w, br_, bi_);
    highB_store(br_, bi_, my, l, w, blkB, b1, h16, h32, OR4, OI4);
}

// ================= pass_low v4: gates {4..13}, coalesced Gray-gather ========
// Block = chunk c (512 blocks, 1024 thr, 16 waves). x_pre = (w<<8)|(j<<6)|l.
// Pre: amp4..7 lane gates (masks 4,8,16,32 -> q18,q17,q16,q15),
//      amp8,9 reg gates (q14,q13).
// RT:  write slot x_pre (contiguous), one barrier, read slot
//      x_post = g8((w<<4)|(l&15)) | l4<<8 | l5<<9 | j'<<10.
// Post: amp10,11 lane gates (masks 16,32 -> q12,q11), amp12,13 reg (q10,q9).
// Store: t = pxor12(x_post) telescopes (verified vs pxor12 at l=0,1,2,16,
//        j'=1,2): t = ((l&15)|(w<<4))^0xFF*S | S<<8 | (l5^j0^j1)<<9
//        | (j0^j1)<<10 | j1<<11, S = l4^l5^j0^j1.
//        addr = t ^ 0xFFF*(c&1); comps (x,y,w,z) reversed iff (t^c)&1.
__global__ __launch_bounds__(1024, 4)
void pass_low(float* __restrict__ sre, float* __restrict__ sim,
              const float* __restrict__ param) {
    __shared__ __align__(16) char L[131072];
    const int tid = threadIdx.x, c = blockIdx.x;
    const int l = tid & 63, w = tid >> 6;
    G8 my = u3_lane(param, l < 23 ? l : 22);
    float4 xr[4], xi[4];

    float4* R4p = (float4*)sre;
    float4* I4p = (float4*)sim;
    const size_t cb = ((size_t)c) << 12;
    const int sw0 = (w << 8) | l;
#pragma unroll
    for (int j = 0; j < 4; ++j) {
        size_t fi = cb | (size_t)(sw0 | (j << 6));
        xr[j] = R4p[fi]; xi[j] = I4p[fi];
    }
    const int h16 = (l >> 4) & 1, h32 = (l >> 5) & 1;

    // pre-RT gates
    { G8 g = gread(my,18); gate_swz4(xr, xi, g, (l >> 2) & 1, 0); }
    { G8 g = gread(my,17); gate_swz8(xr, xi, g, (l >> 3) & 1, 0); }
    { G8 g = gread(my,16); gate_x16(xr, xi, g, h16, h16); }
    { G8 g = gread(my,15); gate_x32(xr, xi, g, h32, h32); }
    { G8 g = gread(my,14); reg_gate0(xr, xi, g); }
    { G8 g = gread(my,13); reg_gate1(xr, xi, g); }

    // RT write (identity layout; re plane, im plane +64 KB) — all global loads
    // are consumed above, so the barrier also makes in-place stores safe.
#pragma unroll
    for (int j = 0; j < 4; ++j) {
        int a = (sw0 | (j << 6)) << 4;
        *(float4*)(L + a) = xr[j];
        *(float4*)(L + a + 65536) = xi[j];
    }
    __syncthreads();
    // RT read at x_post
    const int lw = (w << 4) | (l & 15);
    const int xlow = (lw ^ (lw >> 1)) & 0xFF;
    const int sb = xlow | ((l & 48) << 4);      // l4->bit8, l5->bit9
#pragma unroll
    for (int j = 0; j < 4; ++j) {
        int a = (sb | (j << 10)) << 4;
        xr[j] = *(const float4*)(L + a);
        xi[j] = *(const float4*)(L + a + 65536);
    }

    // post-RT gates
    { G8 g = gread(my,12); gate_x16(xr, xi, g, h16, h16); }
    { G8 g = gread(my,11); gate_x32(xr, xi, g, h32, h32); }
    { G8 g = gread(my,10); reg_gate0(xr, xi, g); }
    { G8 g = gread(my, 9); reg_gate1(xr, xi, g); }

    // Gray-gather store, coalesced (256 B segments per 16-lane group)
    const int codd = c & 1;
    const int A12 = codd ? 0xFFF : 0;
    const int tl = (l & 15) | (w << 4);
#pragma unroll
    for (int j = 0; j < 4; ++j) {
        int j0 = j & 1, j1 = (j >> 1) & 1;
        int S = (h16 ^ h32 ^ j0 ^ j1) & 1;
        int t = (tl ^ (S ? 0xFF : 0))
              | (S << 8)
              | (((h32 ^ j0 ^ j1) & 1) << 9)
              | ((j0 ^ j1) << 10)
              | (j1 << 11);
        int of4 = t ^ A12;
        int b = (t ^ codd) & 1;
        float s0r = xr[j].x, s1r = xr[j].y, s2r = xr[j].w, s3r = xr[j].z;
        float s0i = xi[j].x, s1i = xi[j].y, s2i = xi[j].w, s3i = xi[j].z;
        float o0r = b ? s3r : s0r, o1r = b ? s2r : s1r, o2r = b ? s1r : s2r, o3r = b ? s0r : s3r;
        float o0i = b ? s3i : s0i, o1i = b ? s2i : s1i, o2i = b ? s1i : s2i, o3i = b ? s0i : s3i;
        size_t oo = cb | (size_t)of4;
        R4p[oo] = make_float4(o0r, o1r, o2r, o3r);
        I4p[oo] = make_float4(o0i, o1i, o2i, o3i);
    }
}

extern "C" void kernel_launch(void* const* d_in, const int* in_sizes, int n_in,
                              void* d_out, int out_size, void* d_ws, size_t ws_size,
                              hipStream_t stream) {
    (void)in_sizes; (void)n_in; (void)d_ws; (void)ws_size; (void)out_size;
    const float* in_re = (const float*)d_in[0];
    const float* in_im = (const float*)d_in[1];
    const float* param = (const float*)d_in[2];
    float* out_re = (float*)d_out;
    float* out_im = (float*)d_out + NTOT;

    pass_high<<<256, 1024, 0, stream>>>(in_re, in_im, param, out_re, out_im);
    pass_low <<<512, 1024, 0, stream>>>(out_re, out_im, param);
}

// Round 12
// 77.020 us; speedup vs baseline: 1.2465x; 1.0084x over previous
//
#include <hip/hip_runtime.h>
#include <math.h>

// 23-qubit statevector: 23 U3 gates (qubit q acts on global bit 22-q), then a
// CNOT cascade == Gray permutation out[y] = mid[y ^ (y>>1)].
// R12 partition (rebalanced piecewise-best):
//   pass_high: gates {0,1}u{14..22} (11 gates) — R9 VERBATIM (2-tile fused,
//              3 barriers, chunk Gray-decode sigma=pxor9(row) in stores).
//   pass_low : gates {2..13} (12 gates) — R11 coalesced-store design + the
//              two pre-RT DPP gates q20 (amp2 = lane bit0) and q19 (amp3 =
//              lane bit1), exactly R5's verified assignment.
//              Store: t = pxor12(x_post) telescoped to 256B segments;
//              addr = t ^ 0xFFF*(c&1); comps (x,y,w,z) reversed iff (t^c)&1.

#define NTOT (1u << 23)

typedef unsigned int u2 __attribute__((ext_vector_type(2)));

struct G8 { float r00,i00,r01,i01,r10,i10,r11,i11; };

__device__ __forceinline__ G8 u3_lane(const float* __restrict__ p, int q) {
    float a = p[3*q+0], b = p[3*q+1], c = p[3*q+2];
    float cb = cosf(b*0.5f), sb = sinf(b*0.5f);
    float ph = (a+c)*0.5f, m = (a-c)*0.5f;
    float cp = cosf(ph), sp = sinf(ph);
    float cm = cosf(m),  sm = sinf(m);
    G8 g;
    g.r00 =  cb*cp; g.i00 = -cb*sp;
    g.r01 = -sb*cm; g.i01 =  sb*sm;
    g.r10 =  sb*cm; g.i10 =  sb*sm;
    g.r11 =  cb*cp; g.i11 =  cb*sp;
    return g;
}

__device__ __forceinline__ float rdl(float v, int q) {
    return __uint_as_float(__builtin_amdgcn_readlane(__float_as_uint(v), q));
}
__device__ __forceinline__ G8 gread(const G8& m, int q) {
    G8 g;
    g.r00=rdl(m.r00,q); g.i00=rdl(m.i00,q);
    g.r01=rdl(m.r01,q); g.i01=rdl(m.i01,q);
    g.r10=rdl(m.r10,q); g.i10=rdl(m.i10,q);
    g.r11=rdl(m.r11,q); g.i11=rdl(m.i11,q);
    return g;
}

__device__ __forceinline__ void bfs(float& x0r, float& x0i, float& x1r, float& x1i, const G8& g) {
    float y0r = g.r00*x0r - g.i00*x0i + g.r01*x1r - g.i01*x1i;
    float y0i = g.r00*x0i + g.i00*x0r + g.r01*x1i + g.i01*x1r;
    float y1r = g.r10*x0r - g.i10*x0i + g.r11*x1r - g.i11*x1i;
    float y1i = g.r10*x0i + g.i10*x0r + g.r11*x1i + g.i11*x1r;
    x0r=y0r; x0i=y0i; x1r=y1r; x1i=y1i;
}
__device__ __forceinline__ void bf4v(float4& ar, float4& ai, float4& br, float4& bi, const G8& g) {
    bfs(ar.x, ai.x, br.x, bi.x, g);
    bfs(ar.y, ai.y, br.y, bi.y, g);
    bfs(ar.z, ai.z, br.z, bi.z, g);
    bfs(ar.w, ai.w, br.w, bi.w, g);
}
__device__ __forceinline__ void bfc0(float4& r, float4& i, const G8& g) {
    bfs(r.x, i.x, r.y, i.y, g); bfs(r.z, i.z, r.w, i.w, g);
}
__device__ __forceinline__ void bfc1(float4& r, float4& i, const G8& g) {
    bfs(r.x, i.x, r.z, i.z, g); bfs(r.y, i.y, r.w, i.w, g);
}
__device__ __forceinline__ void reg_gate0(float4 (&xr)[4], float4 (&xi)[4], const G8& g) {
    bf4v(xr[0],xi[0],xr[1],xi[1],g); bf4v(xr[2],xi[2],xr[3],xi[3],g);
}
__device__ __forceinline__ void reg_gate1(float4 (&xr)[4], float4 (&xi)[4], const G8& g) {
    bf4v(xr[0],xi[0],xr[2],xi[2],g); bf4v(xr[1],xi[1],xr[3],xi[3],g);
}

// ---- lane-partner fetchers ----
__device__ __forceinline__ float p_dpp1(float x) {
    return __uint_as_float((unsigned)__builtin_amdgcn_update_dpp(
        0, (int)__float_as_uint(x), 0xB1, 0xF, 0xF, true));   // quad_perm [1,0,3,2]
}
__device__ __forceinline__ float p_dpp2(float x) {
    return __uint_as_float((unsigned)__builtin_amdgcn_update_dpp(
        0, (int)__float_as_uint(x), 0x4E, 0xF, 0xF, true));   // quad_perm [2,3,0,1]
}
__device__ __forceinline__ float p_swz4(float x) {   // xor lane^4 (BitMode)
    return __uint_as_float((unsigned)__builtin_amdgcn_ds_swizzle(
        (int)__float_as_uint(x), 0x101F));
}
__device__ __forceinline__ float p_swz8(float x) {   // xor lane^8 (BitMode)
    return __uint_as_float((unsigned)__builtin_amdgcn_ds_swizzle(
        (int)__float_as_uint(x), 0x201F));
}
__device__ __forceinline__ float p_x16(float x, int hi) {
#if __has_builtin(__builtin_amdgcn_permlane16_swap)
    u2 r = __builtin_amdgcn_permlane16_swap(__float_as_uint(x), __float_as_uint(x), false, false);
    return __uint_as_float(hi ? r[0] : r[1]);
#else
    (void)hi;
    return __uint_as_float((unsigned)__builtin_amdgcn_ds_swizzle(
        (int)__float_as_uint(x), 0x401F));                    // BitMode xor 16
#endif
}
__device__ __forceinline__ float p_x32(float x, int hi) {
#if __has_builtin(__builtin_amdgcn_permlane32_swap)
    u2 r = __builtin_amdgcn_permlane32_swap(__float_as_uint(x), __float_as_uint(x), false, false);
    return __uint_as_float(hi ? r[0] : r[1]);
#else
    (void)hi;
    return __shfl_xor(x, 32, 64);
#endif
}

// lane-bit gate, per-f4 fused fetch+combine (low register pressure)
#define MAKE_PGATE(NAME, FETCH)                                                     \
__device__ __forceinline__ void NAME(float4 (&xr)[4], float4 (&xi)[4],              \
                                     const G8& g, int bit, int hi) {                \
    float cor = bit ? g.r11 : g.r00, coi = bit ? g.i11 : g.i00;                     \
    float cpr = bit ? g.r10 : g.r01, cpi = bit ? g.i10 : g.i01;                     \
    (void)hi;                                                                       \
    _Pragma("unroll")                                                               \
    for (int i = 0; i < 4; ++i) {                                                   \
        float4 pr, pi, nr, ni;                                                      \
        pr.x = FETCH(xr[i].x); pr.y = FETCH(xr[i].y);                               \
        pr.z = FETCH(xr[i].z); pr.w = FETCH(xr[i].w);                               \
        pi.x = FETCH(xi[i].x); pi.y = FETCH(xi[i].y);                               \
        pi.z = FETCH(xi[i].z); pi.w = FETCH(xi[i].w);                               \
        nr.x = cor*xr[i].x - coi*xi[i].x + cpr*pr.x - cpi*pi.x;                     \
        ni.x = cor*xi[i].x + coi*xr[i].x + cpr*pi.x + cpi*pr.x;                     \
        nr.y = cor*xr[i].y - coi*xi[i].y + cpr*pr.y - cpi*pi.y;                     \
        ni.y = cor*xi[i].y + coi*xr[i].y + cpr*pi.y + cpi*pr.y;                     \
        nr.z = cor*xr[i].z - coi*xi[i].z + cpr*pr.z - cpi*pi.z;                     \
        ni.z = cor*xi[i].z + coi*xr[i].z + cpr*pi.z + cpi*pr.z;                     \
        nr.w = cor*xr[i].w - coi*xi[i].w + cpr*pr.w - cpi*pi.w;                     \
        ni.w = cor*xi[i].w + coi*xr[i].w + cpr*pi.w + cpi*pr.w;                     \
        xr[i] = nr; xi[i] = ni;                                                     \
    }                                                                               \
}
#define F_DPP1(v) p_dpp1(v)
#define F_DPP2(v) p_dpp2(v)
#define F_SWZ4(v) p_swz4(v)
#define F_SWZ8(v) p_swz8(v)
#define F_X16(v)  p_x16(v, hi)
#define F_X32(v)  p_x32(v, hi)
MAKE_PGATE(gate_dpp1, F_DPP1)
MAKE_PGATE(gate_dpp2, F_DPP2)
MAKE_PGATE(gate_swz4, F_SWZ4)
MAKE_PGATE(gate_swz8, F_SWZ8)
MAKE_PGATE(gate_x16,  F_X16)
MAKE_PGATE(gate_x32,  F_X32)

__device__ __forceinline__ int pxor9(int x)  { x^=x>>1; x^=x>>2; x^=x>>4; x^=x>>8; return x & 0x1FF; }

// ================= pass_high (R9 verbatim: 11 gates {0,1}u{14..22}) ==========
__device__ __forceinline__ void highA(float4 (&xr)[4], float4 (&xi)[4],
                                      const G8& my, int h16, int h32) {
    { G8 g = gread(my,22);
#pragma unroll
      for (int j = 0; j < 4; ++j) bfc0(xr[j], xi[j], g); }
    { G8 g = gread(my,21);
#pragma unroll
      for (int j = 0; j < 4; ++j) bfc1(xr[j], xi[j], g); }
    { G8 g = gread(my,5); reg_gate0(xr, xi, g); }
    { G8 g = gread(my,4); reg_gate1(xr, xi, g); }
    { G8 g = gread(my,7); gate_x16(xr, xi, g, h16, h16); }
    { G8 g = gread(my,6); gate_x32(xr, xi, g, h32, h32); }
}
__device__ __forceinline__ void wr_high(char* L, int l, int w,
                                        const float4 (&xr)[4], const float4 (&xi)[4]) {
    const int wslot = ((w << 8) | l) << 4;
#pragma unroll
    for (int j = 0; j < 4; ++j) {
        int a = wslot | (j << 10);
        *(float4*)(L + a) = xr[j];
        *(float4*)(L + a + 65536) = xi[j];
    }
}
__device__ __forceinline__ void rd_high(const char* L, int l, int w,
                                        float4 (&xr)[4], float4 (&xi)[4]) {
    const int sbase = (((l >> 1) & 7) | ((w & 3) << 4) | (((w >> 2) & 3) << 6)
                    | (((l >> 4) & 3) << 9) | ((l & 1) << 11)) << 4;
    constexpr int OFF[4] = {0, 8 << 4, 256 << 4, 264 << 4};
#pragma unroll
    for (int j = 0; j < 4; ++j) {
        int a = sbase | OFF[j];
        xr[j] = *(const float4*)(L + a);
        xi[j] = *(const float4*)(L + a + 65536);
    }
}
__device__ __forceinline__ void highB_store(float4 (&xr)[4], float4 (&xi)[4],
        const G8& my, int l, int w, int blk, int b1, int h16, int h32,
        float4* __restrict__ OR4, float4* __restrict__ OI4) {
    { G8 g = gread(my,8); reg_gate0(xr, xi, g); }
    { G8 g = gread(my,3); reg_gate1(xr, xi, g); }
    { G8 g = gread(my,0); gate_dpp1(xr, xi, g, b1, 0); }
    { G8 g = gread(my,2); gate_x16(xr, xi, g, h16, h16); }
    { G8 g = gread(my,1); gate_x32(xr, xi, g, h32, h32); }
    const int row_base = ((w & 15) << 1) | (((l >> 4) & 3) << 6) | ((l & 1) << 8);
    const int sg = pxor9(row_base);
    const size_t ob = ((size_t)blk << 3) | (size_t)((l >> 1) & 7);
    constexpr int SJ[4] = {0, 0x01, 0x3F, 0x3E};
#pragma unroll
    for (int j = 0; j < 4; ++j) {
        size_t F = (((size_t)(sg ^ SJ[j])) << 12) | ob;
        OR4[F] = xr[j]; OI4[F] = xi[j];
    }
}

__global__ __launch_bounds__(1024, 4)
void pass_high(const float* __restrict__ in_re, const float* __restrict__ in_im,
               const float* __restrict__ param,
               float* __restrict__ out_re, float* __restrict__ out_im) {
    __shared__ __align__(16) char L[131072];
    const int tid = threadIdx.x;
    const int l = tid & 63, w = tid >> 6;
    const int blkA = blockIdx.x, blkB = blockIdx.x + 256;

    const float4* R4p = (const float4*)in_re;
    const float4* I4p = (const float4*)in_im;
    float4 ar[4], ai[4], br_[4], bi_[4];
    const int rb = (l >> 3) | (w << 5);
    const size_t gA = ((size_t)blkA << 3) | (size_t)(l & 7);
    const size_t gB = ((size_t)blkB << 3) | (size_t)(l & 7);
#pragma unroll
    for (int j = 0; j < 4; ++j) {
        size_t gi = (((size_t)(rb | (j << 3))) << 12) | gA;
        ar[j] = R4p[gi]; ai[j] = I4p[gi];
    }
#pragma unroll
    for (int j = 0; j < 4; ++j) {
        size_t gi = (((size_t)(rb | (j << 3))) << 12) | gB;
        br_[j] = R4p[gi]; bi_[j] = I4p[gi];
    }
    G8 my = u3_lane(param, l < 23 ? l : 22);   // trig overlaps loads
    const int b1  = l & 1;
    const int h16 = (l >> 4) & 1, h32 = (l >> 5) & 1;
    float4* OR4 = (float4*)out_re;
    float4* OI4 = (float4*)out_im;

    // Tile A
    highA(ar, ai, my, h16, h32);
    wr_high(L, l, w, ar, ai);                  // LDS virgin: no pre-sync
    __syncthreads();
    rd_high(L, l, w, ar, ai);
    highB_store(ar, ai, my, l, w, blkA, b1, h16, h32, OR4, OI4);  // stores async
    // Tile B epoch A overlaps tile A store drain
    highA(br_, bi_, my, h16, h32);
    __syncthreads();                           // all A RT-reads complete
    wr_high(L, l, w, br_, bi_);
    __syncthreads();
    rd_high(L, l, w, br_, bi_);
    highB_store(br_, bi_, my, l, w, blkB, b1, h16, h32, OR4, OI4);
}

// ================= pass_low: gates {2..13}, coalesced Gray-gather ===========
// Block = chunk c (512 blocks, 1024 thr). x_pre = (w<<8)|(j<<6)|l.
// Pre: amp2,3 lane gates (masks 1,2 -> q20,q19: DPP), amp4..7 lane gates
//      (masks 4,8,16,32 -> q18,q17,q16,q15), amp8,9 reg (q14,q13).
// RT:  write slot x_pre (contiguous), one barrier, read slot
//      x_post = g8((w<<4)|(l&15)) | l4<<8 | l5<<9 | j'<<10.
// Post: amp10,11 lane gates (masks 16,32 -> q12,q11), amp12,13 reg (q10,q9).
// Store: t = ((l&15)|(w<<4))^0xFF*S | S<<8 | (l5^j0^j1)<<9 | (j0^j1)<<10
//        | j1<<11, S = l4^l5^j0^j1 (telescoped pxor12, verified R11).
//        addr = t ^ 0xFFF*(c&1); comps (x,y,w,z) reversed iff (t^c)&1.
__global__ __launch_bounds__(1024, 4)
void pass_low(float* __restrict__ sre, float* __restrict__ sim,
              const float* __restrict__ param) {
    __shared__ __align__(16) char L[131072];
    const int tid = threadIdx.x, c = blockIdx.x;
    const int l = tid & 63, w = tid >> 6;
    G8 my = u3_lane(param, l < 23 ? l : 22);
    float4 xr[4], xi[4];

    float4* R4p = (float4*)sre;
    float4* I4p = (float4*)sim;
    const size_t cb = ((size_t)c) << 12;
    const int sw0 = (w << 8) | l;
#pragma unroll
    for (int j = 0; j < 4; ++j) {
        size_t fi = cb | (size_t)(sw0 | (j << 6));
        xr[j] = R4p[fi]; xi[j] = I4p[fi];
    }
    const int b1 = l & 1, b2 = (l >> 1) & 1;
    const int h16 = (l >> 4) & 1, h32 = (l >> 5) & 1;

    // pre-RT gates (12-gate partition: q20..q13 here)
    { G8 g = gread(my,20); gate_dpp1(xr, xi, g, b1, 0); }
    { G8 g = gread(my,19); gate_dpp2(xr, xi, g, b2, 0); }
    { G8 g = gread(my,18); gate_swz4(xr, xi, g, (l >> 2) & 1, 0); }
    { G8 g = gread(my,17); gate_swz8(xr, xi, g, (l >> 3) & 1, 0); }
    { G8 g = gread(my,16); gate_x16(xr, xi, g, h16, h16); }
    { G8 g = gread(my,15); gate_x32(xr, xi, g, h32, h32); }
    { G8 g = gread(my,14); reg_gate0(xr, xi, g); }
    { G8 g = gread(my,13); reg_gate1(xr, xi, g); }

    // RT write (identity layout; re plane, im plane +64 KB) — all global loads
    // consumed above, so the barrier also makes in-place stores safe.
#pragma unroll
    for (int j = 0; j < 4; ++j) {
        int a = (sw0 | (j << 6)) << 4;
        *(float4*)(L + a) = xr[j];
        *(float4*)(L + a + 65536) = xi[j];
    }
    __syncthreads();
    // RT read at x_post
    const int lw = (w << 4) | (l & 15);
    const int xlow = (lw ^ (lw >> 1)) & 0xFF;
    const int sb = xlow | ((l & 48) << 4);      // l4->bit8, l5->bit9
#pragma unroll
    for (int j = 0; j < 4; ++j) {
        int a = (sb | (j << 10)) << 4;
        xr[j] = *(const float4*)(L + a);
        xi[j] = *(const float4*)(L + a + 65536);
    }

    // post-RT gates
    { G8 g = gread(my,12); gate_x16(xr, xi, g, h16, h16); }
    { G8 g = gread(my,11); gate_x32(xr, xi, g, h32, h32); }
    { G8 g = gread(my,10); reg_gate0(xr, xi, g); }
    { G8 g = gread(my, 9); reg_gate1(xr, xi, g); }

    // Gray-gather store, coalesced (256 B segments per 16-lane group)
    const int codd = c & 1;
    const int A12 = codd ? 0xFFF : 0;
    const int tl = (l & 15) | (w << 4);
#pragma unroll
    for (int j = 0; j < 4; ++j) {
        int j0 = j & 1, j1 = (j >> 1) & 1;
        int S = (h16 ^ h32 ^ j0 ^ j1) & 1;
        int t = (tl ^ (S ? 0xFF : 0))
              | (S << 8)
              | (((h32 ^ j0 ^ j1) & 1) << 9)
              | ((j0 ^ j1) << 10)
              | (j1 << 11);
        int of4 = t ^ A12;
        int b = (t ^ codd) & 1;
        float s0r = xr[j].x, s1r = xr[j].y, s2r = xr[j].w, s3r = xr[j].z;
        float s0i = xi[j].x, s1i = xi[j].y, s2i = xi[j].w, s3i = xi[j].z;
        float o0r = b ? s3r : s0r, o1r = b ? s2r : s1r, o2r = b ? s1r : s2r, o3r = b ? s0r : s3r;
        float o0i = b ? s3i : s0i, o1i = b ? s2i : s1i, o2i = b ? s1i : s2i, o3i = b ? s0i : s3i;
        size_t oo = cb | (size_t)of4;
        R4p[oo] = make_float4(o0r, o1r, o2r, o3r);
        I4p[oo] = make_float4(o0i, o1i, o2i, o3i);
    }
}

extern "C" void kernel_launch(void* const* d_in, const int* in_sizes, int n_in,
                              void* d_out, int out_size, void* d_ws, size_t ws_size,
                              hipStream_t stream) {
    (void)in_sizes; (void)n_in; (void)d_ws; (void)ws_size; (void)out_size;
    const float* in_re = (const float*)d_in[0];
    const float* in_im = (const float*)d_in[1];
    const float* param = (const float*)d_in[2];
    float* out_re = (float*)d_out;
    float* out_im = (float*)d_out + NTOT;

    pass_high<<<256, 1024, 0, stream>>>(in_re, in_im, param, out_re, out_im);
    pass_low <<<512, 1024, 0, stream>>>(out_re, out_im, param);
}